// Round 11
// baseline (157.068 us; speedup 1.0000x reference)
//
#include <hip/hip_runtime.h>

#define CC 128
#define OO 128
#define HH 64
#define WW 64
#define HW (HH*WW)

typedef __attribute__((ext_vector_type(8))) __bf16 bf16x8;
typedef __attribute__((ext_vector_type(4))) __bf16 bf16x4;
typedef __attribute__((ext_vector_type(4))) float  f32x4;

// ---------------------------------------------------------------------------
// prep (verbatim R7, passed)
// ---------------------------------------------------------------------------
__global__ __launch_bounds__(256) void prep(
    const float* __restrict__ x,
    const float* __restrict__ gamma, const float* __restrict__ beta,
    const float* __restrict__ mean,  const float* __restrict__ var,
    const float* __restrict__ w_dconv, const float* __restrict__ w_off,
    __bf16* __restrict__ h,            // [b][y][x][c]
    __bf16* __restrict__ wt_bf,        // [kk][o][c]
    __bf16* __restrict__ w_off_b)      // [kk][32][c]
{
    __shared__ float inv_s[128], bb_s[128];
    __shared__ __bf16 tile[64 * 130];
    int blk = blockIdx.x;
    int tid = threadIdx.x;

    if (blk >= 512) {                  // ---- weight transform part ----
        int idx = (blk - 512) * 256 + tid;
        if (idx < 9 * 128 * 128) {
            int c = idx & 127, o = (idx >> 7) & 127, kk = idx >> 14;
            wt_bf[idx] = (__bf16)w_dconv[(o * 128 + c) * 9 + kk];
        }
        if (idx < 9 * 32 * 128) {
            int c = idx & 127, o = (idx >> 7) & 31, kk = idx >> 12;
            float v = (o < 18) ? w_off[o * 1152 + c * 9 + kk] : 0.f;
            w_off_b[idx] = (__bf16)v;
        }
        return;
    }

    // ---- BN+ReLU part ----
    int b = blk & 7, y = blk >> 3;
    if (tid < 128) {
        float iv = gamma[tid] * rsqrtf(var[tid] + 1e-5f);
        inv_s[tid] = iv;
        bb_s[tid]  = beta[tid] - mean[tid] * iv;
    }
    __syncthreads();

    const float* xb = x + (size_t)b * CC * HW + (size_t)y * WW;
    #pragma unroll
    for (int i = 0; i < 8; ++i) {
        int idx = i * 256 + tid;          // 128c x 16 x-quads
        int c = idx >> 4, x4 = idx & 15;
        float4 v = *(const float4*)(xb + (size_t)c * HW + x4 * 4);
        float iv = inv_s[c], bb = bb_s[c];
        tile[(x4 * 4 + 0) * 130 + c] = (__bf16)fmaxf(v.x * iv + bb, 0.f);
        tile[(x4 * 4 + 1) * 130 + c] = (__bf16)fmaxf(v.y * iv + bb, 0.f);
        tile[(x4 * 4 + 2) * 130 + c] = (__bf16)fmaxf(v.z * iv + bb, 0.f);
        tile[(x4 * 4 + 3) * 130 + c] = (__bf16)fmaxf(v.w * iv + bb, 0.f);
    }
    __syncthreads();

    __bf16* hb = h + ((size_t)b * HW + (size_t)y * WW) * CC;
    #pragma unroll
    for (int i = 0; i < 2; ++i) {
        int idx = i * 256 + tid;          // 64x x 8 c16-groups
        int xx = idx >> 3, c16 = idx & 7;
        const uint* src = (const uint*)&tile[xx * 130 + c16 * 16];
        uint r0 = src[0], r1 = src[1], r2 = src[2], r3 = src[3];
        uint r4 = src[4], r5 = src[5], r6 = src[6], r7 = src[7];
        uint* dst = (uint*)(hb + (size_t)xx * CC + c16 * 16);
        *(uint4*)dst       = (uint4){r0, r1, r2, r3};
        *(uint4*)(dst + 4) = (uint4){r4, r5, r6, r7};
    }
}

// ---------------------------------------------------------------------------
// Offset conv (verbatim R7, passed — LDS-staged A and B, 28 us known-good)
// ---------------------------------------------------------------------------
__global__ __launch_bounds__(256) void offset_mfma(
    const __bf16* __restrict__ h,       // [b][y][x][c]
    const __bf16* __restrict__ w_off_b, // [kk][32][128]
    const float* __restrict__ b_off,
    float* __restrict__ offs)           // [b][18][y][x]
{
    __shared__ __align__(16) __bf16 at[64 * 136];
    __shared__ __align__(16) __bf16 bt[32 * 136];
    int blk = blockIdx.x;
    int b = blk & 7, y = blk >> 3;
    int tid = threadIdx.x;
    int lane = tid & 63;
    int wv  = __builtin_amdgcn_readfirstlane(tid >> 6);
    int l15 = lane & 15, quad = lane >> 4;

    const __bf16* hb = h + (size_t)b * HW * CC;

    f32x4 acc[2];
    acc[0] = (f32x4){0.f, 0.f, 0.f, 0.f};
    acc[1] = (f32x4){0.f, 0.f, 0.f, 0.f};

    for (int kk = 0; kk < 9; ++kk) {
        int dy = kk / 3 - 1, dx = kk % 3 - 1;
        int yy = y + dy;
        bool yok = (yy >= 0) && (yy < HH);
        __syncthreads();
        // stage A: 64x x 128c bf16
        #pragma unroll
        for (int i = 0; i < 4; ++i) {
            int idx = i * 256 + tid;
            int xx = idx >> 4, c8 = idx & 15;
            int xs = xx + dx;
            uint4 v = (uint4){0u, 0u, 0u, 0u};
            if (yok && xs >= 0 && xs < WW)
                v = *(const uint4*)(hb + ((size_t)yy * WW + xs) * CC + c8 * 8);
            *(uint4*)&at[xx * 136 + c8 * 8] = v;
        }
        // stage B: 32o x 128c bf16
        const __bf16* wsrc = w_off_b + (size_t)kk * 32 * 128;
        #pragma unroll
        for (int i = 0; i < 2; ++i) {
            int idx = i * 256 + tid;
            int o = idx >> 4, c8 = idx & 15;
            *(uint4*)&bt[o * 136 + c8 * 8] = *(const uint4*)(wsrc + o * 128 + c8 * 8);
        }
        __syncthreads();
        #pragma unroll
        for (int ks = 0; ks < 4; ++ks) {
            int kb = ks * 32 + quad * 8;
            bf16x8 a  = *(const bf16x8*)&at[(wv * 16 + l15) * 136 + kb];
            bf16x8 b0 = *(const bf16x8*)&bt[l15 * 136 + kb];
            bf16x8 b1 = *(const bf16x8*)&bt[(16 + l15) * 136 + kb];
            acc[0] = __builtin_amdgcn_mfma_f32_16x16x32_bf16(a, b0, acc[0], 0, 0, 0);
            acc[1] = __builtin_amdgcn_mfma_f32_16x16x32_bf16(a, b1, acc[1], 0, 0, 0);
        }
    }

    size_t ob = (size_t)b * 18 * HW + (size_t)y * WW;
    #pragma unroll
    for (int nt = 0; nt < 2; ++nt) {
        int oc = nt * 16 + l15;
        if (oc < 18) {
            float bias = b_off[oc];
            #pragma unroll
            for (int r = 0; r < 4; ++r) {
                int xx = wv * 16 + quad * 4 + r;
                offs[ob + (size_t)oc * HW + xx] = acc[nt][r] + bias;
            }
        }
    }
}

// ---------------------------------------------------------------------------
// Deformable conv MFMA — N-SPLIT for occupancy (this round's single change).
// Grid = 1024: b = blk&7, y = (blk>>3)&63, oh = blk>>9 (o-half 0/1).
// Phase-0, gather, vt: VERBATIM R7 (full 64 x per block). Only changes:
// wl shrinks to 64x136 (stage this half's o-rows), each wave covers
// 64x x 16o (b0 only, acc[4]), epilogue o = oh*64 + wv*16 + l15.
// LDS = 9216+9216+17408+17408 = 53.2 KB -> 3 blocks/CU = 12 waves/CU.
// ---------------------------------------------------------------------------
__global__ __launch_bounds__(256, 2) void deform_conv_mfma(
    const __bf16* __restrict__ h,      // [b][y][x][c] bf16
    const float* __restrict__ offs,    // [b][18][y][x]
    const __bf16* __restrict__ wt,     // [kk][o][c] bf16
    const float* __restrict__ b_dconv,
    float* __restrict__ out)           // NCHW fp32
{
    __shared__ float pw[576 * 4];
    __shared__ int   pidx[576 * 4];
    __shared__ __align__(16) __bf16 vt[64 * 136];
    __shared__ __align__(16) __bf16 wl[64 * 136];

    int blk = blockIdx.x;
    int b = blk & 7, y = (blk >> 3) & 63, oh = blk >> 9;
    int tid = threadIdx.x;

    const __bf16* hb = h + (size_t)b * HW * CC;
    size_t offbase = (size_t)b * 18 * HW + (size_t)y * WW;

    // ---- phase 0: bilinear params (verbatim R7) ----
    for (int e = tid; e < 576; e += 256) {
        int kk = e >> 6, xx = e & 63;
        float dy = offs[offbase + (size_t)(2 * kk) * HW + xx];
        float dx = offs[offbase + (size_t)(2 * kk + 1) * HW + xx];
        float py = dy + (float)y + (float)(kk / 3 - 1);
        float px = dx + (float)xx + (float)(kk % 3 - 1);
        float fy = floorf(py), fx = floorf(px);
        int y0 = (int)fy, x0 = (int)fx;
        float wy = py - fy, wx = px - fx;
        int y1 = y0 + 1, x1 = x0 + 1;
        bool vy0 = (y0 >= 0) && (y0 < HH);
        bool vy1 = (y1 >= 0) && (y1 < HH);
        bool vx0 = (x0 >= 0) && (x0 < WW);
        bool vx1 = (x1 >= 0) && (x1 < WW);
        int yc0 = min(max(y0, 0), HH - 1), yc1 = min(max(y1, 0), HH - 1);
        int xc0 = min(max(x0, 0), WW - 1), xc1 = min(max(x1, 0), WW - 1);
        pw[e * 4 + 0] = (vy0 && vx0) ? (1.f - wy) * (1.f - wx) : 0.f;
        pw[e * 4 + 1] = (vy0 && vx1) ? (1.f - wy) * wx         : 0.f;
        pw[e * 4 + 2] = (vy1 && vx0) ? wy * (1.f - wx)         : 0.f;
        pw[e * 4 + 3] = (vy1 && vx1) ? wy * wx                 : 0.f;
        pidx[e * 4 + 0] = (yc0 * WW + xc0) * CC;
        pidx[e * 4 + 1] = (yc0 * WW + xc1) * CC;
        pidx[e * 4 + 2] = (yc1 * WW + xc0) * CC;
        pidx[e * 4 + 3] = (yc1 * WW + xc1) * CC;
    }

    int lane = tid & 63;
    int wv   = __builtin_amdgcn_readfirstlane(tid >> 6);
    int l15  = lane & 15, quad = lane >> 4;
    int cl   = tid & 31, xh = tid >> 5;

    f32x4 acc[4];
    #pragma unroll
    for (int mt = 0; mt < 4; ++mt) acc[mt] = (f32x4){0.f, 0.f, 0.f, 0.f};

    for (int kk = 0; kk < 9; ++kk) {
        __syncthreads();
        // ---- stage w half-chunk: 64o x 128c bf16, 16B coalesced ----
        const uint4* wsrc = (const uint4*)(wt + ((size_t)kk * OO + oh * 64) * CC);
        #pragma unroll
        for (int j = 0; j < 4; ++j) {
            int idx = j * 256 + tid;          // 1024 = 64 rows x 16 c8-segs
            int cs = idx & 15, o = idx >> 4;
            *(uint4*)&wl[o * 136 + cs * 8] = wsrc[idx];
        }
        // ---- gather v chunk (verbatim R7): 64x x 128c ----
        #pragma unroll
        for (int j = 0; j < 8; ++j) {
            int xx = xh * 8 + j;
            int e = (kk << 6) + xx;
            float w0 = pw[e * 4 + 0], w1 = pw[e * 4 + 1];
            float w2 = pw[e * 4 + 2], w3 = pw[e * 4 + 3];
            bf16x4 t0 = *(const bf16x4*)(hb + pidx[e * 4 + 0] + cl * 4);
            bf16x4 t1 = *(const bf16x4*)(hb + pidx[e * 4 + 1] + cl * 4);
            bf16x4 t2 = *(const bf16x4*)(hb + pidx[e * 4 + 2] + cl * 4);
            bf16x4 t3 = *(const bf16x4*)(hb + pidx[e * 4 + 3] + cl * 4);
            float rx = w0 * (float)t0[0] + w1 * (float)t1[0] + w2 * (float)t2[0] + w3 * (float)t3[0];
            float ry = w0 * (float)t0[1] + w1 * (float)t1[1] + w2 * (float)t2[1] + w3 * (float)t3[1];
            float rz = w0 * (float)t0[2] + w1 * (float)t1[2] + w2 * (float)t2[2] + w3 * (float)t3[2];
            float rw = w0 * (float)t0[3] + w1 * (float)t1[3] + w2 * (float)t2[3] + w3 * (float)t3[3];
            bf16x4 pk = {(__bf16)rx, (__bf16)ry, (__bf16)rz, (__bf16)rw};
            *(bf16x4*)&vt[xx * 136 + cl * 4] = pk;
        }
        __syncthreads();
        // ---- MFMA: 4 K-steps of 32; wave covers 64x x 16o ----
        #pragma unroll
        for (int ks = 0; ks < 4; ++ks) {
            int kb = ks * 32 + quad * 8;
            bf16x8 a0 = *(const bf16x8*)&vt[(0 * 16 + l15) * 136 + kb];
            bf16x8 a1 = *(const bf16x8*)&vt[(1 * 16 + l15) * 136 + kb];
            bf16x8 a2 = *(const bf16x8*)&vt[(2 * 16 + l15) * 136 + kb];
            bf16x8 a3 = *(const bf16x8*)&vt[(3 * 16 + l15) * 136 + kb];
            bf16x8 b0 = *(const bf16x8*)&wl[(wv * 16 + l15) * 136 + kb];
            acc[0] = __builtin_amdgcn_mfma_f32_16x16x32_bf16(a0, b0, acc[0], 0, 0, 0);
            acc[1] = __builtin_amdgcn_mfma_f32_16x16x32_bf16(a1, b0, acc[1], 0, 0, 0);
            acc[2] = __builtin_amdgcn_mfma_f32_16x16x32_bf16(a2, b0, acc[2], 0, 0, 0);
            acc[3] = __builtin_amdgcn_mfma_f32_16x16x32_bf16(a3, b0, acc[3], 0, 0, 0);
        }
    }

    // epilogue: x = mt*16 + quad*4 + r (float4), o = oh*64 + wv*16 + l15
    size_t ob = (size_t)b * OO * HW + (size_t)y * WW;
    int o = oh * 64 + wv * 16 + l15;
    float bias = b_dconv[o];
    #pragma unroll
    for (int mt = 0; mt < 4; ++mt) {
        int xb = mt * 16 + quad * 4;
        float4 r;
        r.x = acc[mt][0] + bias;
        r.y = acc[mt][1] + bias;
        r.z = acc[mt][2] + bias;
        r.w = acc[mt][3] + bias;
        *(float4*)&out[ob + (size_t)o * HW + xb] = r;
    }
}

// ---------------------------------------------------------------------------
extern "C" void kernel_launch(void* const* d_in, const int* in_sizes, int n_in,
                              void* d_out, int out_size, void* d_ws, size_t ws_size,
                              hipStream_t stream)
{
    const float* x       = (const float*)d_in[0];
    const float* gamma   = (const float*)d_in[1];
    const float* beta    = (const float*)d_in[2];
    const float* mean    = (const float*)d_in[3];
    const float* var     = (const float*)d_in[4];
    const float* w_off   = (const float*)d_in[5];
    const float* b_off   = (const float*)d_in[6];
    const float* w_dconv = (const float*)d_in[7];
    const float* b_dconv = (const float*)d_in[8];
    float* out = (float*)d_out;

    char* ws = (char*)d_ws;
    __bf16* h_bf    = (__bf16*)ws;                 // 8,388,608 B
    float*  offs    = (float*)(ws + 8388608);      // 2,359,296 B
    __bf16* wt_bf   = (__bf16*)(ws + 10747904);    //   294,912 B
    __bf16* w_off_b = (__bf16*)(ws + 11042816);    //    73,728 B

    prep<<<1232, 256, 0, stream>>>(x, gamma, beta, mean, var,
                                   w_dconv, w_off, h_bf, wt_bf, w_off_b);
    offset_mfma<<<512, 256, 0, stream>>>(h_bf, w_off_b, b_off, offs);
    deform_conv_mfma<<<1024, 256, 0, stream>>>(h_bf, offs, wt_bf, b_dconv, out);
}

// Round 12
// 127.705 us; speedup vs baseline: 1.2299x; 1.2299x over previous
//
#include <hip/hip_runtime.h>

#define CC 128
#define OO 128
#define HH 64
#define WW 64
#define HW (HH*WW)

typedef __attribute__((ext_vector_type(8))) __bf16 bf16x8;
typedef __attribute__((ext_vector_type(4))) __bf16 bf16x4;
typedef __attribute__((ext_vector_type(4))) float  f32x4;

// ---------------------------------------------------------------------------
// prep: blocks 0..511  -> BN+ReLU into h NHWC bf16 (verbatim R7)
//       blocks 512..   -> weight relayouts into MFMA-FRAGMENT-SWIZZLED order:
//   wt_swz  [kk][ks][og0..7][lane0..63][j0..7]: element = w_dconv[o][c][kk]
//       with o = og*16 + (lane&15), c = ks*32 + (lane>>4)*8 + j
//   woff_swz[kk][ks][og0..1][lane0..63][j0..7]: same, from w_off (o>=18 -> 0)
// A wave's B-frag load is then 64 lanes x 16 B contiguous = one 1KB txn.
// ---------------------------------------------------------------------------
__global__ __launch_bounds__(256) void prep(
    const float* __restrict__ x,
    const float* __restrict__ gamma, const float* __restrict__ beta,
    const float* __restrict__ mean,  const float* __restrict__ var,
    const float* __restrict__ w_dconv, const float* __restrict__ w_off,
    __bf16* __restrict__ h,            // [b][y][x][c]
    __bf16* __restrict__ wt_swz,       // 147456 elems
    __bf16* __restrict__ woff_swz)     // 36864 elems
{
    __shared__ float inv_s[128], bb_s[128];
    __shared__ __bf16 tile[64 * 130];
    int blk = blockIdx.x;
    int tid = threadIdx.x;

    if (blk >= 512) {                  // ---- weight swizzle part ----
        int idx = (blk - 512) * 256 + tid;
        if (idx < 147456) {            // 9kk x 4ks x 8og x 64lane x 8j
            int j    = idx & 7;
            int lane = (idx >> 3) & 63;
            int og   = (idx >> 9) & 7;
            int ks   = (idx >> 12) & 3;
            int kk   = idx >> 14;
            int o = og * 16 + (lane & 15);
            int c = ks * 32 + (lane >> 4) * 8 + j;
            wt_swz[idx] = (__bf16)w_dconv[(o * 128 + c) * 9 + kk];
        }
        if (idx < 36864) {             // 9kk x 4ks x 2og x 64lane x 8j
            int j    = idx & 7;
            int lane = (idx >> 3) & 63;
            int og   = (idx >> 9) & 1;
            int ks   = (idx >> 10) & 3;
            int kk   = idx >> 12;
            int o = og * 16 + (lane & 15);
            int c = ks * 32 + (lane >> 4) * 8 + j;
            float v = (o < 18) ? w_off[o * 1152 + c * 9 + kk] : 0.f;
            woff_swz[idx] = (__bf16)v;
        }
        return;
    }

    // ---- BN+ReLU part (verbatim R7) ----
    int b = blk & 7, y = blk >> 3;
    if (tid < 128) {
        float iv = gamma[tid] * rsqrtf(var[tid] + 1e-5f);
        inv_s[tid] = iv;
        bb_s[tid]  = beta[tid] - mean[tid] * iv;
    }
    __syncthreads();

    const float* xb = x + (size_t)b * CC * HW + (size_t)y * WW;
    #pragma unroll
    for (int i = 0; i < 8; ++i) {
        int idx = i * 256 + tid;          // 128c x 16 x-quads
        int c = idx >> 4, x4 = idx & 15;
        float4 v = *(const float4*)(xb + (size_t)c * HW + x4 * 4);
        float iv = inv_s[c], bb = bb_s[c];
        tile[(x4 * 4 + 0) * 130 + c] = (__bf16)fmaxf(v.x * iv + bb, 0.f);
        tile[(x4 * 4 + 1) * 130 + c] = (__bf16)fmaxf(v.y * iv + bb, 0.f);
        tile[(x4 * 4 + 2) * 130 + c] = (__bf16)fmaxf(v.z * iv + bb, 0.f);
        tile[(x4 * 4 + 3) * 130 + c] = (__bf16)fmaxf(v.w * iv + bb, 0.f);
    }
    __syncthreads();

    __bf16* hb = h + ((size_t)b * HW + (size_t)y * WW) * CC;
    #pragma unroll
    for (int i = 0; i < 2; ++i) {
        int idx = i * 256 + tid;          // 64x x 8 c16-groups
        int xx = idx >> 3, c16 = idx & 7;
        const uint* src = (const uint*)&tile[xx * 130 + c16 * 16];
        uint r0 = src[0], r1 = src[1], r2 = src[2], r3 = src[3];
        uint r4 = src[4], r5 = src[5], r6 = src[6], r7 = src[7];
        uint* dst = (uint*)(hb + (size_t)xx * CC + c16 * 16);
        *(uint4*)dst       = (uint4){r0, r1, r2, r3};
        *(uint4*)(dst + 4) = (uint4){r4, r5, r6, r7};
    }
}

// ---------------------------------------------------------------------------
// Offset conv MFMA: A staging verbatim R7 but double-buffered (1 barrier/kk);
// B-frags from swizzled global (coalesced 1KB wave loads, L2-hot 72KB).
// Per (b,y) block: 64x x 32oc x 1152k. Numerics/K-order identical to R7.
// ---------------------------------------------------------------------------
__global__ __launch_bounds__(256) void offset_mfma(
    const __bf16* __restrict__ h,        // [b][y][x][c]
    const __bf16* __restrict__ woff_swz, // fragment-swizzled
    const float* __restrict__ b_off,
    float* __restrict__ offs)            // [b][18][y][x]
{
    __shared__ __align__(16) __bf16 at[2][64 * 136];
    int blk = blockIdx.x;
    int b = blk & 7, y = blk >> 3;
    int tid = threadIdx.x;
    int lane = tid & 63;
    int wv  = __builtin_amdgcn_readfirstlane(tid >> 6);
    int l15 = lane & 15, quad = lane >> 4;

    const __bf16* hb = h + (size_t)b * HW * CC;
    const bf16x8* w8 = (const bf16x8*)woff_swz;

    f32x4 acc[2];
    acc[0] = (f32x4){0.f, 0.f, 0.f, 0.f};
    acc[1] = (f32x4){0.f, 0.f, 0.f, 0.f};

    for (int kk = 0; kk < 9; ++kk) {
        int buf = kk & 1;
        int dy = kk / 3 - 1, dx = kk % 3 - 1;
        int yy = y + dy;
        bool yok = (yy >= 0) && (yy < HH);
        // stage A: 64x x 128c bf16 (verbatim R7 masking)
        #pragma unroll
        for (int i = 0; i < 4; ++i) {
            int idx = i * 256 + tid;
            int xx = idx >> 4, c8 = idx & 15;
            int xs = xx + dx;
            uint4 v = (uint4){0u, 0u, 0u, 0u};
            if (yok && xs >= 0 && xs < WW)
                v = *(const uint4*)(hb + ((size_t)yy * WW + xs) * CC + c8 * 8);
            *(uint4*)&at[buf][xx * 136 + c8 * 8] = v;
        }
        __syncthreads();                  // one barrier per kk
        #pragma unroll
        for (int ks = 0; ks < 4; ++ks) {
            int kb = ks * 32 + quad * 8;
            bf16x8 a  = *(const bf16x8*)&at[buf][(wv * 16 + l15) * 136 + kb];
            bf16x8 b0 = w8[((kk * 4 + ks) * 2 + 0) * 64 + lane];
            bf16x8 b1 = w8[((kk * 4 + ks) * 2 + 1) * 64 + lane];
            acc[0] = __builtin_amdgcn_mfma_f32_16x16x32_bf16(a, b0, acc[0], 0, 0, 0);
            acc[1] = __builtin_amdgcn_mfma_f32_16x16x32_bf16(a, b1, acc[1], 0, 0, 0);
        }
    }

    size_t ob = (size_t)b * 18 * HW + (size_t)y * WW;
    #pragma unroll
    for (int nt = 0; nt < 2; ++nt) {
        int oc = nt * 16 + l15;
        if (oc < 18) {
            float bias = b_off[oc];
            #pragma unroll
            for (int r = 0; r < 4; ++r) {
                int xx = wv * 16 + quad * 4 + r;
                offs[ob + (size_t)oc * HW + xx] = acc[nt][r] + bias;
            }
        }
    }
}

// ---------------------------------------------------------------------------
// Deformable conv MFMA (R7 shape, leaner K-loop):
//  - B-frags from swizzled global (wl LDS tile ELIMINATED: -72 loads,
//    -72 LDS writes per thread)
//  - gather taps widened to bf16x8 (16 loads/thread/kk instead of 32)
//  - vt double-buffered -> ONE barrier per kk (10 total vs 18)
// Phase-0 and epilogue verbatim R7. LDS = 9216+9216+2*17408 = 67.6 KB.
// ---------------------------------------------------------------------------
__global__ __launch_bounds__(256, 2) void deform_conv_mfma(
    const __bf16* __restrict__ h,      // [b][y][x][c] bf16
    const float* __restrict__ offs,    // [b][18][y][x]
    const __bf16* __restrict__ wt_swz, // fragment-swizzled
    const float* __restrict__ b_dconv,
    float* __restrict__ out)           // NCHW fp32
{
    __shared__ float pw[576 * 4];
    __shared__ int   pidx[576 * 4];
    __shared__ __align__(16) __bf16 vt[2][64 * 136];

    int blk = blockIdx.x;
    int b = blk & 7, y = blk >> 3;
    int tid = threadIdx.x;

    const __bf16* hb = h + (size_t)b * HW * CC;
    size_t offbase = (size_t)b * 18 * HW + (size_t)y * WW;

    // ---- phase 0: bilinear params (verbatim R7) ----
    for (int e = tid; e < 576; e += 256) {
        int kk = e >> 6, xx = e & 63;
        float dy = offs[offbase + (size_t)(2 * kk) * HW + xx];
        float dx = offs[offbase + (size_t)(2 * kk + 1) * HW + xx];
        float py = dy + (float)y + (float)(kk / 3 - 1);
        float px = dx + (float)xx + (float)(kk % 3 - 1);
        float fy = floorf(py), fx = floorf(px);
        int y0 = (int)fy, x0 = (int)fx;
        float wy = py - fy, wx = px - fx;
        int y1 = y0 + 1, x1 = x0 + 1;
        bool vy0 = (y0 >= 0) && (y0 < HH);
        bool vy1 = (y1 >= 0) && (y1 < HH);
        bool vx0 = (x0 >= 0) && (x0 < WW);
        bool vx1 = (x1 >= 0) && (x1 < WW);
        int yc0 = min(max(y0, 0), HH - 1), yc1 = min(max(y1, 0), HH - 1);
        int xc0 = min(max(x0, 0), WW - 1), xc1 = min(max(x1, 0), WW - 1);
        pw[e * 4 + 0] = (vy0 && vx0) ? (1.f - wy) * (1.f - wx) : 0.f;
        pw[e * 4 + 1] = (vy0 && vx1) ? (1.f - wy) * wx         : 0.f;
        pw[e * 4 + 2] = (vy1 && vx0) ? wy * (1.f - wx)         : 0.f;
        pw[e * 4 + 3] = (vy1 && vx1) ? wy * wx                 : 0.f;
        pidx[e * 4 + 0] = (yc0 * WW + xc0) * CC;
        pidx[e * 4 + 1] = (yc0 * WW + xc1) * CC;
        pidx[e * 4 + 2] = (yc1 * WW + xc0) * CC;
        pidx[e * 4 + 3] = (yc1 * WW + xc1) * CC;
    }
    __syncthreads();                     // pw/pidx visible to all

    int lane = tid & 63;
    int wv   = __builtin_amdgcn_readfirstlane(tid >> 6);
    int l15  = lane & 15, quad = lane >> 4;
    const bf16x8* w8 = (const bf16x8*)wt_swz;

    f32x4 acc[4][2];
    #pragma unroll
    for (int mt = 0; mt < 4; ++mt)
        #pragma unroll
        for (int nt = 0; nt < 2; ++nt)
            acc[mt][nt] = (f32x4){0.f, 0.f, 0.f, 0.f};

    for (int kk = 0; kk < 9; ++kk) {
        int buf = kk & 1;
        // ---- gather v chunk: 64x x 128c; bf16x8 taps, fp32 blend ----
        #pragma unroll
        for (int i = 0; i < 4; ++i) {
            int idx = i * 256 + tid;         // 1024 = 64x x 16 c8-segs
            int xx = idx >> 4, c8 = idx & 15;
            int e = (kk << 6) + xx;
            float w0 = pw[e * 4 + 0], w1 = pw[e * 4 + 1];
            float w2 = pw[e * 4 + 2], w3 = pw[e * 4 + 3];
            bf16x8 t0 = *(const bf16x8*)(hb + pidx[e * 4 + 0] + c8 * 8);
            bf16x8 t1 = *(const bf16x8*)(hb + pidx[e * 4 + 1] + c8 * 8);
            bf16x8 t2 = *(const bf16x8*)(hb + pidx[e * 4 + 2] + c8 * 8);
            bf16x8 t3 = *(const bf16x8*)(hb + pidx[e * 4 + 3] + c8 * 8);
            bf16x8 pk;
            #pragma unroll
            for (int q = 0; q < 8; ++q) {
                float v = w0 * (float)t0[q] + w1 * (float)t1[q]
                        + w2 * (float)t2[q] + w3 * (float)t3[q];
                pk[q] = (__bf16)v;
            }
            *(bf16x8*)&vt[buf][xx * 136 + c8 * 8] = pk;
        }
        __syncthreads();                 // one barrier per kk
        // ---- MFMA: 4 K-steps of 32; wave covers 64x x 32o ----
        #pragma unroll
        for (int ks = 0; ks < 4; ++ks) {
            int kb = ks * 32 + quad * 8;
            bf16x8 b0 = w8[((kk * 4 + ks) * 8 + 2 * wv + 0) * 64 + lane];
            bf16x8 b1 = w8[((kk * 4 + ks) * 8 + 2 * wv + 1) * 64 + lane];
            bf16x8 a0 = *(const bf16x8*)&vt[buf][(0 * 16 + l15) * 136 + kb];
            bf16x8 a1 = *(const bf16x8*)&vt[buf][(1 * 16 + l15) * 136 + kb];
            bf16x8 a2 = *(const bf16x8*)&vt[buf][(2 * 16 + l15) * 136 + kb];
            bf16x8 a3 = *(const bf16x8*)&vt[buf][(3 * 16 + l15) * 136 + kb];
            acc[0][0] = __builtin_amdgcn_mfma_f32_16x16x32_bf16(a0, b0, acc[0][0], 0, 0, 0);
            acc[1][0] = __builtin_amdgcn_mfma_f32_16x16x32_bf16(a1, b0, acc[1][0], 0, 0, 0);
            acc[2][0] = __builtin_amdgcn_mfma_f32_16x16x32_bf16(a2, b0, acc[2][0], 0, 0, 0);
            acc[3][0] = __builtin_amdgcn_mfma_f32_16x16x32_bf16(a3, b0, acc[3][0], 0, 0, 0);
            acc[0][1] = __builtin_amdgcn_mfma_f32_16x16x32_bf16(a0, b1, acc[0][1], 0, 0, 0);
            acc[1][1] = __builtin_amdgcn_mfma_f32_16x16x32_bf16(a1, b1, acc[1][1], 0, 0, 0);
            acc[2][1] = __builtin_amdgcn_mfma_f32_16x16x32_bf16(a2, b1, acc[2][1], 0, 0, 0);
            acc[3][1] = __builtin_amdgcn_mfma_f32_16x16x32_bf16(a3, b1, acc[3][1], 0, 0, 0);
        }
    }

    // ---- epilogue (verbatim R7) ----
    size_t ob = (size_t)b * OO * HW + (size_t)y * WW;
    #pragma unroll
    for (int nt = 0; nt < 2; ++nt) {
        int o = wv * 32 + nt * 16 + l15;
        float bias = b_dconv[o];
        #pragma unroll
        for (int mt = 0; mt < 4; ++mt) {
            int xb = mt * 16 + quad * 4;
            float4 r;
            r.x = acc[mt][nt][0] + bias;
            r.y = acc[mt][nt][1] + bias;
            r.z = acc[mt][nt][2] + bias;
            r.w = acc[mt][nt][3] + bias;
            *(float4*)&out[ob + (size_t)o * HW + xb] = r;
        }
    }
}

// ---------------------------------------------------------------------------
extern "C" void kernel_launch(void* const* d_in, const int* in_sizes, int n_in,
                              void* d_out, int out_size, void* d_ws, size_t ws_size,
                              hipStream_t stream)
{
    const float* x       = (const float*)d_in[0];
    const float* gamma   = (const float*)d_in[1];
    const float* beta    = (const float*)d_in[2];
    const float* mean    = (const float*)d_in[3];
    const float* var     = (const float*)d_in[4];
    const float* w_off   = (const float*)d_in[5];
    const float* b_off   = (const float*)d_in[6];
    const float* w_dconv = (const float*)d_in[7];
    const float* b_dconv = (const float*)d_in[8];
    float* out = (float*)d_out;

    char* ws = (char*)d_ws;
    __bf16* h_bf     = (__bf16*)ws;                 // 8,388,608 B
    float*  offs     = (float*)(ws + 8388608);      // 2,359,296 B
    __bf16* wt_swz   = (__bf16*)(ws + 10747904);    //   294,912 B
    __bf16* woff_swz = (__bf16*)(ws + 11042816);    //    73,728 B

    prep<<<1232, 256, 0, stream>>>(x, gamma, beta, mean, var,
                                   w_dconv, w_off, h_bf, wt_swz, woff_swz);
    offset_mfma<<<512, 256, 0, stream>>>(h_bf, woff_swz, b_off, offs);
    deform_conv_mfma<<<512, 256, 0, stream>>>(h_bf, offs, wt_swz, b_dconv, out);
}

// Round 13
// 125.424 us; speedup vs baseline: 1.2523x; 1.0182x over previous
//
#include <hip/hip_runtime.h>

#define CC 128
#define OO 128
#define HH 64
#define WW 64
#define HW (HH*WW)

typedef __attribute__((ext_vector_type(8))) __bf16 bf16x8;
typedef __attribute__((ext_vector_type(4))) __bf16 bf16x4;
typedef __attribute__((ext_vector_type(4))) float  f32x4;

// ---------------------------------------------------------------------------
// prep (verbatim R12, passed): BN+ReLU -> h NHWC bf16; weight relayouts into
// MFMA-fragment-swizzled order (wave B-frag load = one contiguous 1KB txn).
// ---------------------------------------------------------------------------
__global__ __launch_bounds__(256) void prep(
    const float* __restrict__ x,
    const float* __restrict__ gamma, const float* __restrict__ beta,
    const float* __restrict__ mean,  const float* __restrict__ var,
    const float* __restrict__ w_dconv, const float* __restrict__ w_off,
    __bf16* __restrict__ h,            // [b][y][x][c]
    __bf16* __restrict__ wt_swz,       // 147456 elems
    __bf16* __restrict__ woff_swz)     // 36864 elems
{
    __shared__ float inv_s[128], bb_s[128];
    __shared__ __bf16 tile[64 * 130];
    int blk = blockIdx.x;
    int tid = threadIdx.x;

    if (blk >= 512) {                  // ---- weight swizzle part ----
        int idx = (blk - 512) * 256 + tid;
        if (idx < 147456) {            // 9kk x 4ks x 8og x 64lane x 8j
            int j    = idx & 7;
            int lane = (idx >> 3) & 63;
            int og   = (idx >> 9) & 7;
            int ks   = (idx >> 12) & 3;
            int kk   = idx >> 14;
            int o = og * 16 + (lane & 15);
            int c = ks * 32 + (lane >> 4) * 8 + j;
            wt_swz[idx] = (__bf16)w_dconv[(o * 128 + c) * 9 + kk];
        }
        if (idx < 36864) {             // 9kk x 4ks x 2og x 64lane x 8j
            int j    = idx & 7;
            int lane = (idx >> 3) & 63;
            int og   = (idx >> 9) & 1;
            int ks   = (idx >> 10) & 3;
            int kk   = idx >> 12;
            int o = og * 16 + (lane & 15);
            int c = ks * 32 + (lane >> 4) * 8 + j;
            float v = (o < 18) ? w_off[o * 1152 + c * 9 + kk] : 0.f;
            woff_swz[idx] = (__bf16)v;
        }
        return;
    }

    // ---- BN+ReLU part ----
    int b = blk & 7, y = blk >> 3;
    if (tid < 128) {
        float iv = gamma[tid] * rsqrtf(var[tid] + 1e-5f);
        inv_s[tid] = iv;
        bb_s[tid]  = beta[tid] - mean[tid] * iv;
    }
    __syncthreads();

    const float* xb = x + (size_t)b * CC * HW + (size_t)y * WW;
    #pragma unroll
    for (int i = 0; i < 8; ++i) {
        int idx = i * 256 + tid;          // 128c x 16 x-quads
        int c = idx >> 4, x4 = idx & 15;
        float4 v = *(const float4*)(xb + (size_t)c * HW + x4 * 4);
        float iv = inv_s[c], bb = bb_s[c];
        tile[(x4 * 4 + 0) * 130 + c] = (__bf16)fmaxf(v.x * iv + bb, 0.f);
        tile[(x4 * 4 + 1) * 130 + c] = (__bf16)fmaxf(v.y * iv + bb, 0.f);
        tile[(x4 * 4 + 2) * 130 + c] = (__bf16)fmaxf(v.z * iv + bb, 0.f);
        tile[(x4 * 4 + 3) * 130 + c] = (__bf16)fmaxf(v.w * iv + bb, 0.f);
    }
    __syncthreads();

    __bf16* hb = h + ((size_t)b * HW + (size_t)y * WW) * CC;
    #pragma unroll
    for (int i = 0; i < 2; ++i) {
        int idx = i * 256 + tid;          // 64x x 8 c16-groups
        int xx = idx >> 3, c16 = idx & 7;
        const uint* src = (const uint*)&tile[xx * 130 + c16 * 16];
        uint r0 = src[0], r1 = src[1], r2 = src[2], r3 = src[3];
        uint r4 = src[4], r5 = src[5], r6 = src[6], r7 = src[7];
        uint* dst = (uint*)(hb + (size_t)xx * CC + c16 * 16);
        *(uint4*)dst       = (uint4){r0, r1, r2, r3};
        *(uint4*)(dst + 4) = (uint4){r4, r5, r6, r7};
    }
}

// ---------------------------------------------------------------------------
// Offset conv MFMA, software-pipelined staging:
//  prologue loads A(kk=0) into regs; loop = {write at[buf] from regs;
//  issue A(kk+1) loads; lgkm-drain + RAW s_barrier (global loads stay in
//  flight across it); MFMA(kk)}. B-frags from swizzled global (1KB txns).
// Numerics/K-order identical to R12.
// ---------------------------------------------------------------------------
__global__ __launch_bounds__(256) void offset_mfma(
    const __bf16* __restrict__ h,        // [b][y][x][c]
    const __bf16* __restrict__ woff_swz, // fragment-swizzled
    const float* __restrict__ b_off,
    float* __restrict__ offs)            // [b][18][y][x]
{
    __shared__ __align__(16) __bf16 at[2][64 * 136];
    int blk = blockIdx.x;
    int b = blk & 7, y = blk >> 3;
    int tid = threadIdx.x;
    int lane = tid & 63;
    int wv  = __builtin_amdgcn_readfirstlane(tid >> 6);
    int l15 = lane & 15, quad = lane >> 4;

    const __bf16* hb = h + (size_t)b * HW * CC;
    const bf16x8* w8 = (const bf16x8*)woff_swz;

    int sxx = tid >> 4, sc8 = tid & 15;   // this thread's staging row/seg
    // (256 threads cover 64x x 4 c8-segs per i; 4 i-steps cover 16 segs)

    f32x4 acc[2];
    acc[0] = (f32x4){0.f, 0.f, 0.f, 0.f};
    acc[1] = (f32x4){0.f, 0.f, 0.f, 0.f};

    uint4 pa[4];
    // ---- prologue: masked loads for kk = 0 (dy=-1, dx=-1) ----
    {
        int yy = y - 1;
        bool yok = (yy >= 0);
        #pragma unroll
        for (int i = 0; i < 4; ++i) {
            int idx = i * 256 + tid;
            int xx = idx >> 4, c8 = idx & 15;
            int xs = xx - 1;
            pa[i] = (uint4){0u, 0u, 0u, 0u};
            if (yok && xs >= 0)
                pa[i] = *(const uint4*)(hb + ((size_t)yy * WW + xs) * CC + c8 * 8);
        }
    }

    for (int kk = 0; kk < 9; ++kk) {
        int buf = kk & 1;
        // ---- write staged A from regs ----
        #pragma unroll
        for (int i = 0; i < 4; ++i) {
            int idx = i * 256 + tid;
            int xx = idx >> 4, c8 = idx & 15;
            *(uint4*)&at[buf][xx * 136 + c8 * 8] = pa[i];
        }
        // ---- issue loads for kk+1 (fly across the barrier) ----
        if (kk < 8) {
            int k2 = kk + 1;
            int dy = k2 / 3 - 1, dx = k2 % 3 - 1;
            int yy = y + dy;
            bool yok = (yy >= 0) && (yy < HH);
            #pragma unroll
            for (int i = 0; i < 4; ++i) {
                int idx = i * 256 + tid;
                int xx = idx >> 4, c8 = idx & 15;
                int xs = xx + dx;
                pa[i] = (uint4){0u, 0u, 0u, 0u};
                if (yok && xs >= 0 && xs < WW)
                    pa[i] = *(const uint4*)(hb + ((size_t)yy * WW + xs) * CC + c8 * 8);
            }
        }
        asm volatile("s_waitcnt lgkmcnt(0)" ::: "memory");  // LDS writes visible
        __builtin_amdgcn_s_barrier();                       // no vmcnt drain
        // ---- MFMA(kk) ----
        #pragma unroll
        for (int ks = 0; ks < 4; ++ks) {
            int kb = ks * 32 + quad * 8;
            bf16x8 a  = *(const bf16x8*)&at[buf][(wv * 16 + l15) * 136 + kb];
            bf16x8 b0 = w8[((kk * 4 + ks) * 2 + 0) * 64 + lane];
            bf16x8 b1 = w8[((kk * 4 + ks) * 2 + 1) * 64 + lane];
            acc[0] = __builtin_amdgcn_mfma_f32_16x16x32_bf16(a, b0, acc[0], 0, 0, 0);
            acc[1] = __builtin_amdgcn_mfma_f32_16x16x32_bf16(a, b1, acc[1], 0, 0, 0);
        }
    }

    size_t ob = (size_t)b * 18 * HW + (size_t)y * WW;
    #pragma unroll
    for (int nt = 0; nt < 2; ++nt) {
        int oc = nt * 16 + l15;
        if (oc < 18) {
            float bias = b_off[oc];
            #pragma unroll
            for (int r = 0; r < 4; ++r) {
                int xx = wv * 16 + quad * 4 + r;
                offs[ob + (size_t)oc * HW + xx] = acc[nt][r] + bias;
            }
        }
    }
}

// ---------------------------------------------------------------------------
// Deformable conv MFMA, software-pipelined gather:
//  prologue loads taps(kk=0) into regs; loop = {blend+write vt[buf];
//  issue taps(kk+1); lgkm-drain + RAW s_barrier; MFMA(kk)}.
//  Tap loads stay in flight across barrier + MFMA. B-frags swizzled-global.
// Safety: each wave's lgkmcnt(0) before barrier covers both its vt writes
// and its prior vt reads, so post-barrier overwrite of the other buffer is
// race-free. Numerics identical to R12.
// ---------------------------------------------------------------------------
__global__ __launch_bounds__(256, 2) void deform_conv_mfma(
    const __bf16* __restrict__ h,      // [b][y][x][c] bf16
    const float* __restrict__ offs,    // [b][18][y][x]
    const __bf16* __restrict__ wt_swz, // fragment-swizzled
    const float* __restrict__ b_dconv,
    float* __restrict__ out)           // NCHW fp32
{
    __shared__ float pw[576 * 4];
    __shared__ int   pidx[576 * 4];
    __shared__ __align__(16) __bf16 vt[2][64 * 136];

    int blk = blockIdx.x;
    int b = blk & 7, y = blk >> 3;
    int tid = threadIdx.x;

    const __bf16* hb = h + (size_t)b * HW * CC;
    size_t offbase = (size_t)b * 18 * HW + (size_t)y * WW;

    // ---- phase 0: bilinear params (verbatim R12) ----
    for (int e = tid; e < 576; e += 256) {
        int kk = e >> 6, xx = e & 63;
        float dy = offs[offbase + (size_t)(2 * kk) * HW + xx];
        float dx = offs[offbase + (size_t)(2 * kk + 1) * HW + xx];
        float py = dy + (float)y + (float)(kk / 3 - 1);
        float px = dx + (float)xx + (float)(kk % 3 - 1);
        float fy = floorf(py), fx = floorf(px);
        int y0 = (int)fy, x0 = (int)fx;
        float wy = py - fy, wx = px - fx;
        int y1 = y0 + 1, x1 = x0 + 1;
        bool vy0 = (y0 >= 0) && (y0 < HH);
        bool vy1 = (y1 >= 0) && (y1 < HH);
        bool vx0 = (x0 >= 0) && (x0 < WW);
        bool vx1 = (x1 >= 0) && (x1 < WW);
        int yc0 = min(max(y0, 0), HH - 1), yc1 = min(max(y1, 0), HH - 1);
        int xc0 = min(max(x0, 0), WW - 1), xc1 = min(max(x1, 0), WW - 1);
        pw[e * 4 + 0] = (vy0 && vx0) ? (1.f - wy) * (1.f - wx) : 0.f;
        pw[e * 4 + 1] = (vy0 && vx1) ? (1.f - wy) * wx         : 0.f;
        pw[e * 4 + 2] = (vy1 && vx0) ? wy * (1.f - wx)         : 0.f;
        pw[e * 4 + 3] = (vy1 && vx1) ? wy * wx                 : 0.f;
        pidx[e * 4 + 0] = (yc0 * WW + xc0) * CC;
        pidx[e * 4 + 1] = (yc0 * WW + xc1) * CC;
        pidx[e * 4 + 2] = (yc1 * WW + xc0) * CC;
        pidx[e * 4 + 3] = (yc1 * WW + xc1) * CC;
    }
    __syncthreads();                     // pw/pidx visible to all

    int lane = tid & 63;
    int wv   = __builtin_amdgcn_readfirstlane(tid >> 6);
    int l15  = lane & 15, quad = lane >> 4;
    const bf16x8* w8 = (const bf16x8*)wt_swz;

    f32x4 acc[4][2];
    #pragma unroll
    for (int mt = 0; mt < 4; ++mt)
        #pragma unroll
        for (int nt = 0; nt < 2; ++nt)
            acc[mt][nt] = (f32x4){0.f, 0.f, 0.f, 0.f};

    bf16x8 pt0[4], pt1[4], pt2[4], pt3[4];
    // ---- prologue: tap loads for kk = 0 ----
    #pragma unroll
    for (int i = 0; i < 4; ++i) {
        int idx = i * 256 + tid;
        int xx = idx >> 4, c8 = idx & 15;
        int e = xx;                      // kk = 0
        pt0[i] = *(const bf16x8*)(hb + pidx[e * 4 + 0] + c8 * 8);
        pt1[i] = *(const bf16x8*)(hb + pidx[e * 4 + 1] + c8 * 8);
        pt2[i] = *(const bf16x8*)(hb + pidx[e * 4 + 2] + c8 * 8);
        pt3[i] = *(const bf16x8*)(hb + pidx[e * 4 + 3] + c8 * 8);
    }

    for (int kk = 0; kk < 9; ++kk) {
        int buf = kk & 1;
        // ---- blend prefetched taps -> vt[buf] ----
        #pragma unroll
        for (int i = 0; i < 4; ++i) {
            int idx = i * 256 + tid;
            int xx = idx >> 4, c8 = idx & 15;
            int e = (kk << 6) + xx;
            float w0 = pw[e * 4 + 0], w1 = pw[e * 4 + 1];
            float w2 = pw[e * 4 + 2], w3 = pw[e * 4 + 3];
            bf16x8 pk;
            #pragma unroll
            for (int q = 0; q < 8; ++q) {
                float v = w0 * (float)pt0[i][q] + w1 * (float)pt1[i][q]
                        + w2 * (float)pt2[i][q] + w3 * (float)pt3[i][q];
                pk[q] = (__bf16)v;
            }
            *(bf16x8*)&vt[buf][xx * 136 + c8 * 8] = pk;
        }
        // ---- issue tap loads for kk+1 (fly across the barrier) ----
        if (kk < 8) {
            #pragma unroll
            for (int i = 0; i < 4; ++i) {
                int idx = i * 256 + tid;
                int xx = idx >> 4, c8 = idx & 15;
                int e2 = ((kk + 1) << 6) + xx;
                pt0[i] = *(const bf16x8*)(hb + pidx[e2 * 4 + 0] + c8 * 8);
                pt1[i] = *(const bf16x8*)(hb + pidx[e2 * 4 + 1] + c8 * 8);
                pt2[i] = *(const bf16x8*)(hb + pidx[e2 * 4 + 2] + c8 * 8);
                pt3[i] = *(const bf16x8*)(hb + pidx[e2 * 4 + 3] + c8 * 8);
            }
        }
        asm volatile("s_waitcnt lgkmcnt(0)" ::: "memory");  // LDS writes visible
        __builtin_amdgcn_s_barrier();                       // no vmcnt drain
        // ---- MFMA(kk): 4 K-steps; wave covers 64x x 32o ----
        #pragma unroll
        for (int ks = 0; ks < 4; ++ks) {
            int kb = ks * 32 + quad * 8;
            bf16x8 b0 = w8[((kk * 4 + ks) * 8 + 2 * wv + 0) * 64 + lane];
            bf16x8 b1 = w8[((kk * 4 + ks) * 8 + 2 * wv + 1) * 64 + lane];
            bf16x8 a0 = *(const bf16x8*)&vt[buf][(0 * 16 + l15) * 136 + kb];
            bf16x8 a1 = *(const bf16x8*)&vt[buf][(1 * 16 + l15) * 136 + kb];
            bf16x8 a2 = *(const bf16x8*)&vt[buf][(2 * 16 + l15) * 136 + kb];
            bf16x8 a3 = *(const bf16x8*)&vt[buf][(3 * 16 + l15) * 136 + kb];
            acc[0][0] = __builtin_amdgcn_mfma_f32_16x16x32_bf16(a0, b0, acc[0][0], 0, 0, 0);
            acc[1][0] = __builtin_amdgcn_mfma_f32_16x16x32_bf16(a1, b0, acc[1][0], 0, 0, 0);
            acc[2][0] = __builtin_amdgcn_mfma_f32_16x16x32_bf16(a2, b0, acc[2][0], 0, 0, 0);
            acc[3][0] = __builtin_amdgcn_mfma_f32_16x16x32_bf16(a3, b0, acc[3][0], 0, 0, 0);
            acc[0][1] = __builtin_amdgcn_mfma_f32_16x16x32_bf16(a0, b1, acc[0][1], 0, 0, 0);
            acc[1][1] = __builtin_amdgcn_mfma_f32_16x16x32_bf16(a1, b1, acc[1][1], 0, 0, 0);
            acc[2][1] = __builtin_amdgcn_mfma_f32_16x16x32_bf16(a2, b1, acc[2][1], 0, 0, 0);
            acc[3][1] = __builtin_amdgcn_mfma_f32_16x16x32_bf16(a3, b1, acc[3][1], 0, 0, 0);
        }
    }

    // ---- epilogue (verbatim R12) ----
    size_t ob = (size_t)b * OO * HW + (size_t)y * WW;
    #pragma unroll
    for (int nt = 0; nt < 2; ++nt) {
        int o = wv * 32 + nt * 16 + l15;
        float bias = b_dconv[o];
        #pragma unroll
        for (int mt = 0; mt < 4; ++mt) {
            int xb = mt * 16 + quad * 4;
            float4 r;
            r.x = acc[mt][nt][0] + bias;
            r.y = acc[mt][nt][1] + bias;
            r.z = acc[mt][nt][2] + bias;
            r.w = acc[mt][nt][3] + bias;
            *(float4*)&out[ob + (size_t)o * HW + xb] = r;
        }
    }
}

// ---------------------------------------------------------------------------
extern "C" void kernel_launch(void* const* d_in, const int* in_sizes, int n_in,
                              void* d_out, int out_size, void* d_ws, size_t ws_size,
                              hipStream_t stream)
{
    const float* x       = (const float*)d_in[0];
    const float* gamma   = (const float*)d_in[1];
    const float* beta    = (const float*)d_in[2];
    const float* mean    = (const float*)d_in[3];
    const float* var     = (const float*)d_in[4];
    const float* w_off   = (const float*)d_in[5];
    const float* b_off   = (const float*)d_in[6];
    const float* w_dconv = (const float*)d_in[7];
    const float* b_dconv = (const float*)d_in[8];
    float* out = (float*)d_out;

    char* ws = (char*)d_ws;
    __bf16* h_bf     = (__bf16*)ws;                 // 8,388,608 B
    float*  offs     = (float*)(ws + 8388608);      // 2,359,296 B
    __bf16* wt_swz   = (__bf16*)(ws + 10747904);    //   294,912 B
    __bf16* woff_swz = (__bf16*)(ws + 11042816);    //    73,728 B

    prep<<<1232, 256, 0, stream>>>(x, gamma, beta, mean, var,
                                   w_dconv, w_off, h_bf, wt_swz, woff_swz);
    offset_mfma<<<512, 256, 0, stream>>>(h_bf, woff_swz, b_off, offs);
    deform_conv_mfma<<<512, 256, 0, stream>>>(h_bf, offs, wt_swz, b_dconv, out);
}